// Round 5
// baseline (952.085 us; speedup 1.0000x reference)
//
#include <hip/hip_runtime.h>
#include <hip/hip_bf16.h>
#include <hip/hip_fp16.h>

#define NN 100000
#define NE 1600000
#define FIN 128
#define HD 64
#define NB_SCAN 391    // ceil(NN/256)
#define NBUCK 782      // ceil(NN/128): 128 dest-nodes per bucket
#define BCAP 4096      // bucket capacity (mean 2046, sigma 45 -> 45-sigma headroom)

typedef unsigned int uint32;

// ---------------- bucket-partitioned CSR build ----------------
// pass 1: scatter packed (row<<7 | col&127) into per-bucket staging
__global__ void k_part(const int* __restrict__ row, const int* __restrict__ col,
                       int* __restrict__ bcnt, uint32* __restrict__ staged){
    int e = blockIdx.x*256 + threadIdx.x;
    if(e < NE){
        int c = col[e], r = row[e];
        int b = c >> 7;
        int pos = atomicAdd(&bcnt[b], 1);
        if(pos < BCAP) staged[(size_t)b*BCAP + pos] = ((uint32)r << 7) | (uint32)(c & 127);
    }
}

// pass 1.5: per-bucket LDS histogram -> deg
__global__ void __launch_bounds__(256) k_hist(const int* __restrict__ bcnt,
                                              const uint32* __restrict__ staged,
                                              int* __restrict__ deg){
    __shared__ int h[128];
    int b = blockIdx.x, t = threadIdx.x;
    if(t < 128) h[t] = 0;
    __syncthreads();
    int cnt = min(bcnt[b], BCAP);
    const uint32* st = staged + (size_t)b*BCAP;
    for(int i = t; i < cnt; i += 256) atomicAdd(&h[st[i] & 127u], 1);
    __syncthreads();
    int n = b*128 + t;
    if(t < 128 && n < NN) deg[n] = h[t];
}

// pass 2: per-bucket scatter in LDS, coalesced write-out
__global__ void __launch_bounds__(256) k_fill2(const int* __restrict__ bcnt,
                                               const uint32* __restrict__ staged,
                                               const int* __restrict__ starts,
                                               int* __restrict__ csr){
    __shared__ int cur[128];
    __shared__ int lcsr[BCAP];
    int b = blockIdx.x, t = threadIdx.x;
    int n0 = b*128;
    int base = starts[n0];            // n0 < NN always (NBUCK = ceil(NN/128))
    if(t < 128 && n0 + t < NN) cur[t] = starts[n0 + t] - base;
    __syncthreads();
    int cnt = min(bcnt[b], BCAP);
    const uint32* st = staged + (size_t)b*BCAP;
    for(int i = t; i < cnt; i += 256){
        uint32 u = st[i];
        int lc = (int)(u & 127u);
        int r  = (int)(u >> 7);
        int p  = atomicAdd(&cur[lc], 1);
        lcsr[p] = r;
    }
    __syncthreads();
    for(int i = t; i < cnt; i += 256) csr[base + i] = lcsr[i];
}

// ---------------- scan chain (deg -> starts, dinv) ----------------

__global__ void k_bsum(const int* __restrict__ deg, int* __restrict__ bsum){
    __shared__ int r[256];
    int t = threadIdx.x; int i = blockIdx.x*256 + t;
    r[t] = (i < NN) ? deg[i] : 0;
    __syncthreads();
    for(int off=128; off>0; off>>=1){ if(t<off) r[t]+=r[t+off]; __syncthreads(); }
    if(t==0) bsum[blockIdx.x] = r[0];
}

__global__ void k_top(int* __restrict__ bsum){
    __shared__ int s[512];
    int t = threadIdx.x;
    int v = (t < NB_SCAN) ? bsum[t] : 0;
    s[t] = v; __syncthreads();
    for(int off=1; off<512; off<<=1){
        int a = (t>=off)? s[t-off] : 0;
        __syncthreads();
        s[t] += a;
        __syncthreads();
    }
    if(t < NB_SCAN) bsum[t] = s[t] - v;   // exclusive scan of block sums
}

__global__ void k_scan(const int* __restrict__ deg, const int* __restrict__ bsum,
                       int* __restrict__ starts, float* __restrict__ dinv){
    __shared__ int s[256];
    int t = threadIdx.x; int i = blockIdx.x*256 + t;
    int d = (i<NN)? deg[i] : 0;
    s[t] = d; __syncthreads();
    for(int off=1; off<256; off<<=1){
        int a = (t>=off)? s[t-off] : 0;
        __syncthreads();
        s[t] += a;
        __syncthreads();
    }
    if(i < NN){
        starts[i] = bsum[blockIdx.x] + s[t] - d;   // exclusive
        dinv[i] = rsqrtf((float)(d + 1));          // +1 self-loop
    }
}

// ---------------- BN constant folding ----------------
__global__ void k_const(const float* __restrict__ encB, const float* __restrict__ encG,
                        const float* __restrict__ encBe, const float* __restrict__ encM,
                        const float* __restrict__ encV,
                        const float* __restrict__ ep1b, const float* __restrict__ epG,
                        const float* __restrict__ epBe, const float* __restrict__ epM,
                        const float* __restrict__ epV,
                        float* __restrict__ foldEnc, float* __restrict__ foldPre){
    int j = threadIdx.x;
    if(j < 64){
        float s = encG[j]*rsqrtf(encV[j]+1e-5f);
        foldEnc[j]      = s;
        foldEnc[64+j]   = (encB[j]-encM[j])*s + encBe[j];
        float sp = epG[j]*rsqrtf(epV[j]+1e-5f);
        foldPre[j]      = sp;
        foldPre[64+j]   = sp;
        foldPre[128+j]  = sp*(ep1b[j]-epM[j]) + epBe[j];
        foldPre[192+j]  = 0.f;
    }
}

// ---------------- generic GEMV: thread-per-node, W staged in LDS ----------------
// PREMAP: W source is ep1W [128,64]; logical W[k][j] = j<64 ? ep1W[k][j] : ep1W[64+k][j-64]
template<int K, int JB, bool PREMAP, bool FOLD, bool RELU, bool OH>
__global__ void __launch_bounds__(256) k_gemv(const float* __restrict__ in,
                                              const float* __restrict__ W,
                                              const float* __restrict__ fold,
                                              void* __restrict__ outv){
    __shared__ float Ws[K*JB*64];
    __shared__ float Fs[2*JB*64];
    const int J = JB*64;
    for(int idx = threadIdx.x; idx < K*J; idx += 256){
        if(PREMAP){
            int k = idx / J, j = idx % J;   // J=128 here
            Ws[idx] = (j < 64) ? W[k*64 + j] : W[(64+k)*64 + (j-64)];
        } else {
            Ws[idx] = W[idx];
        }
    }
    if(FOLD){
        for(int idx = threadIdx.x; idx < 2*J; idx += 256) Fs[idx] = fold[idx];
    }
    __syncthreads();
    int n = blockIdx.x*256 + threadIdx.x;
    if(n >= NN) return;
    const float4* x4 = (const float4*)(in + (size_t)n*K);
    for(int jb = 0; jb < JB; jb++){
        float acc[64];
        #pragma unroll
        for(int j = 0; j < 64; j++) acc[j] = 0.f;
        for(int k4 = 0; k4 < K/4; k4++){
            float4 xv = x4[k4];
            #pragma unroll
            for(int kk = 0; kk < 4; kk++){
                float xs_ = (kk==0)?xv.x:(kk==1)?xv.y:(kk==2)?xv.z:xv.w;
                const float4* wrow = (const float4*)&Ws[(k4*4+kk)*J + jb*64];
                #pragma unroll
                for(int j4 = 0; j4 < 16; j4++){
                    float4 w = wrow[j4];
                    acc[4*j4+0] = fmaf(xs_, w.x, acc[4*j4+0]);
                    acc[4*j4+1] = fmaf(xs_, w.y, acc[4*j4+1]);
                    acc[4*j4+2] = fmaf(xs_, w.z, acc[4*j4+2]);
                    acc[4*j4+3] = fmaf(xs_, w.w, acc[4*j4+3]);
                }
            }
        }
        #pragma unroll
        for(int j4 = 0; j4 < 16; j4++){
            float vv[4];
            #pragma unroll
            for(int c = 0; c < 4; c++){
                int j = 4*j4 + c;
                float t = acc[j];
                if(FOLD) t = t*Fs[jb*64+j] + Fs[J + jb*64 + j];
                if(RELU) t = fmaxf(t, 0.f);
                vv[c] = t;
            }
            if(OH){
                ushort4 u;
                u.x = __half_as_ushort(__float2half_rn(vv[0]));
                u.y = __half_as_ushort(__float2half_rn(vv[1]));
                u.z = __half_as_ushort(__float2half_rn(vv[2]));
                u.w = __half_as_ushort(__float2half_rn(vv[3]));
                ((ushort4*)((unsigned short*)outv + (size_t)n*J + jb*64))[j4] = u;
            } else {
                float4 v;
                v.x = vv[0]; v.y = vv[1]; v.z = vv[2]; v.w = vv[3];
                ((float4*)((float*)outv + (size_t)n*J + jb*64))[j4] = v;
            }
        }
    }
}

// ---------------- GCN aggregation (fp16 hw): relu(sum_in + self + b) ----------------
__global__ void __launch_bounds__(256) k_agg(const __half* __restrict__ hw,
                                             const int* __restrict__ starts,
                                             const int* __restrict__ deg,
                                             const int* __restrict__ csr,
                                             const float* __restrict__ dinv,
                                             const float* __restrict__ bias,
                                             float* __restrict__ out){
    int t = threadIdx.x, w = t>>6, f = t&63;
    int n = blockIdx.x*4 + w;
    int s = starts[n], d = deg[n];
    float acc = 0.f;
    int i = 0;
    for(; i+3 < d; i += 4){                 // 4-way unroll for outstanding gathers
        int r0 = csr[s+i],   r1 = csr[s+i+1];
        int r2 = csr[s+i+2], r3 = csr[s+i+3];
        float v0 = __half2float(hw[(size_t)r0*64 + f]);
        float v1 = __half2float(hw[(size_t)r1*64 + f]);
        float v2 = __half2float(hw[(size_t)r2*64 + f]);
        float v3 = __half2float(hw[(size_t)r3*64 + f]);
        acc = fmaf(v0, dinv[r0], acc);
        acc = fmaf(v1, dinv[r1], acc);
        acc = fmaf(v2, dinv[r2], acc);
        acc = fmaf(v3, dinv[r3], acc);
    }
    for(; i < d; i++){
        int r0 = csr[s+i];
        acc = fmaf(__half2float(hw[(size_t)r0*64 + f]), dinv[r0], acc);
    }
    float dn = dinv[n];
    float self = __half2float(hw[(size_t)n*64 + f]);
    float v = acc*dn + self*dn*dn + bias[f];
    out[(size_t)n*64 + f] = fmaxf(v, 0.f);
}

// ---------------- edge predictor (factorized, fp16 pre): thread-per-edge ----------------
__global__ void __launch_bounds__(256) k_edge2(const __half* __restrict__ pre,
                                               const int* __restrict__ row,
                                               const int* __restrict__ col,
                                               const float* __restrict__ w2,
                                               const float* __restrict__ b2,
                                               float* __restrict__ out){
    __shared__ float w2s[64];
    __shared__ float b2s;
    if(threadIdx.x < 64) w2s[threadIdx.x] = w2[threadIdx.x];
    if(threadIdx.x == 64) b2s = b2[0];
    __syncthreads();
    int e = blockIdx.x*256 + threadIdx.x;
    if(e >= NE) return;
    int r = row[e], c = col[e];
    const uint4* pa = (const uint4*)(pre + (size_t)r*128);        // A half: 128B
    const uint4* pb = (const uint4*)(pre + (size_t)c*128 + 64);   // B half: 128B
    float z = 0.f;
    #pragma unroll
    for(int q = 0; q < 8; q++){                  // 8 x uint4 = 8 fp16 each
        uint4 ua = pa[q], ub = pb[q];
        const __half2* ah = (const __half2*)&ua;
        const __half2* bh = (const __half2*)&ub;
        #pragma unroll
        for(int u = 0; u < 4; u++){
            float2 a2 = __half22float2(ah[u]);
            float2 b2v = __half22float2(bh[u]);
            int j = q*8 + u*2;
            z = fmaf(fmaxf(a2.x + b2v.x, 0.f), w2s[j],   z);
            z = fmaf(fmaxf(a2.y + b2v.y, 0.f), w2s[j+1], z);
        }
    }
    z += b2s;
    out[e] = 1.f / (1.f + __expf(-z));
}

// ---------------- launch ----------------

extern "C" void kernel_launch(void* const* d_in, const int* in_sizes, int n_in,
                              void* d_out, int out_size, void* d_ws, size_t ws_size,
                              hipStream_t stream){
    const float* x   = (const float*)d_in[0];
    const int* ei    = (const int*)d_in[1];
    const int* row   = ei;
    const int* col   = ei + NE;
    const float* encW = (const float*)d_in[2],  *encB = (const float*)d_in[3];
    const float* encG = (const float*)d_in[4],  *encBe= (const float*)d_in[5];
    const float* encM = (const float*)d_in[6],  *encV = (const float*)d_in[7];
    const float* c1W  = (const float*)d_in[8],  *c1b  = (const float*)d_in[9];
    const float* c2W  = (const float*)d_in[10], *c2b  = (const float*)d_in[11];
    const float* ep1W = (const float*)d_in[12], *ep1b = (const float*)d_in[13];
    const float* epG  = (const float*)d_in[14], *epBe = (const float*)d_in[15];
    const float* epM  = (const float*)d_in[16], *epV  = (const float*)d_in[17];
    const float* ep2W = (const float*)d_in[18], *ep2b = (const float*)d_in[19];

    char* wsc = (char*)d_ws;
    size_t o = 0;
    auto alloc = [&](size_t bytes)->void*{
        void* p = wsc + o; o += (bytes + 255) & ~(size_t)255; return p;
    };
    int*    deg     = (int*)   alloc((size_t)NN*4);
    int*    starts  = (int*)   alloc((size_t)NN*4);
    int*    bsum    = (int*)   alloc(1024*4);
    int*    bcnt    = (int*)   alloc((size_t)NBUCK*4);
    int*    csr     = (int*)   alloc((size_t)NE*4);
    uint32* staged  = (uint32*)alloc((size_t)NBUCK*BCAP*4);   // 12.8 MB
    float*  dinv    = (float*) alloc((size_t)NN*4);
    float*  foldEnc = (float*) alloc(128*4);
    float*  foldPre = (float*) alloc(256*4);
    float*  bufA    = (float*) alloc((size_t)NN*64*4);        // fp32 h buffer (25.6 MB)
    __half* bufB    = (__half*)alloc((size_t)NN*64*2);        // fp16 hw buffer (12.8 MB)
    // pre[N,128] fp16 (25.6 MB) aliases bufA (dead after conv2 gemv)
    __half* preh    = (__half*)bufA;
    // total ~58.9 MB of d_ws

    float* outp = (float*)d_out;               // [NN*64] node emb | [NE] edge preds
    float* node_out = outp;
    float* edge_out = outp + (size_t)NN*64;

    hipMemsetAsync(bcnt, 0, (size_t)NBUCK*4, stream);
    k_part <<<(NE+255)/256, 256, 0, stream>>>(row, col, bcnt, staged);
    k_hist <<<NBUCK,        256, 0, stream>>>(bcnt, staged, deg);
    k_bsum <<<NB_SCAN,      256, 0, stream>>>(deg, bsum);
    k_top  <<<1,            512, 0, stream>>>(bsum);
    k_scan <<<NB_SCAN,      256, 0, stream>>>(deg, bsum, starts, dinv);
    k_fill2<<<NBUCK,        256, 0, stream>>>(bcnt, staged, starts, csr);
    k_const<<<1, 64, 0, stream>>>(encB, encG, encBe, encM, encV,
                                  ep1b, epG, epBe, epM, epV, foldEnc, foldPre);

    // encoder: relu(bn(x @ encW + b)) -> fp32 bufA
    k_gemv<128,1,false,true,true,false><<<NB_SCAN, 256, 0, stream>>>(x, encW, foldEnc, bufA);

    // conv1: hw fp16 -> aggregate fp32
    k_gemv<64,1,false,false,false,true><<<NB_SCAN, 256, 0, stream>>>(bufA, c1W, nullptr, bufB);
    k_agg  <<<NN/4, 256, 0, stream>>>(bufB, starts, deg, csr, dinv, c1b, bufA);

    // conv2
    k_gemv<64,1,false,false,false,true><<<NB_SCAN, 256, 0, stream>>>(bufA, c2W, nullptr, bufB);
    k_agg  <<<NN/4, 256, 0, stream>>>(bufB, starts, deg, csr, dinv, c2b, node_out);

    // edge predictor precompute -> fp16 pre
    k_gemv<64,2,true,true,false,true><<<NB_SCAN, 256, 0, stream>>>(node_out, ep1W, foldPre, preh);

    // per-edge: sigmoid(sum relu(preA[r]+preB[c])*w2 + b2)
    k_edge2<<<NE/256, 256, 0, stream>>>(preh, row, col, ep2W, ep2b, edge_out);
}

// Round 6
// 612.712 us; speedup vs baseline: 1.5539x; 1.5539x over previous
//
#include <hip/hip_runtime.h>
#include <hip/hip_bf16.h>
#include <hip/hip_fp16.h>

#define NN 100000
#define NE 1600000
#define FIN 128
#define HD 64
#define NB_SCAN 391    // ceil(NN/256)
#define BSH 9          // bucket covers 512 dest nodes
#define NBUCK 196      // ceil(NN/512)
#define BCAP 10240     // per-bucket staging cap (mean 8163, sigma 128 -> +16 sigma)
#define CHUNK 8192     // edges per stage-1 block
#define NCHUNK 196     // ceil(NE/CHUNK)

typedef unsigned int uint32;

// ---------------- stage 1: block-level counting sort into 196 buckets ----------------
__global__ void __launch_bounds__(256) k_part(const int* __restrict__ row,
                                              const int* __restrict__ col,
                                              int* __restrict__ bcnt,
                                              uint32* __restrict__ staged){
    __shared__ int hist[NBUCK];
    __shared__ int base[NBUCK];
    int t = threadIdx.x;
    int e0 = blockIdx.x * CHUNK;
    int e1 = min(e0 + CHUNK, NE);
    for(int i = t; i < NBUCK; i += 256) hist[i] = 0;
    __syncthreads();
    for(int e = e0 + t; e < e1; e += 256)
        atomicAdd(&hist[col[e] >> BSH], 1);
    __syncthreads();
    for(int i = t; i < NBUCK; i += 256){
        int c = hist[i];
        base[i] = (c > 0) ? atomicAdd(&bcnt[i], c) : 0;   // one global atomic per (block,bucket)
        hist[i] = 0;                                       // reuse as cursor
    }
    __syncthreads();
    for(int e = e0 + t; e < e1; e += 256){
        int c = col[e], r = row[e];
        int b = c >> BSH;
        int pos = base[b] + atomicAdd(&hist[b], 1);
        if(pos < BCAP)
            staged[(size_t)b*BCAP + pos] = ((uint32)r << BSH) | (uint32)(c & 511);
    }
}

// ---------------- stage 2a: per-bucket LDS histogram -> deg ----------------
__global__ void __launch_bounds__(256) k_hist(const int* __restrict__ bcnt,
                                              const uint32* __restrict__ staged,
                                              int* __restrict__ deg){
    __shared__ int h[512];
    int b = blockIdx.x, t = threadIdx.x;
    for(int i = t; i < 512; i += 256) h[i] = 0;
    __syncthreads();
    int cnt = min(bcnt[b], BCAP);
    const uint32* st = staged + (size_t)b*BCAP;
    for(int i = t; i < cnt; i += 256) atomicAdd(&h[st[i] & 511u], 1);
    __syncthreads();
    for(int i = t; i < 512; i += 256){
        int n = b*512 + i;
        if(n < NN) deg[n] = h[i];
    }
}

// ---------------- scan chain (deg -> starts, dinv) ----------------
__global__ void k_bsum(const int* __restrict__ deg, int* __restrict__ bsum){
    __shared__ int r[256];
    int t = threadIdx.x; int i = blockIdx.x*256 + t;
    r[t] = (i < NN) ? deg[i] : 0;
    __syncthreads();
    for(int off=128; off>0; off>>=1){ if(t<off) r[t]+=r[t+off]; __syncthreads(); }
    if(t==0) bsum[blockIdx.x] = r[0];
}

__global__ void k_top(int* __restrict__ bsum){
    __shared__ int s[512];
    int t = threadIdx.x;
    int v = (t < NB_SCAN) ? bsum[t] : 0;
    s[t] = v; __syncthreads();
    for(int off=1; off<512; off<<=1){
        int a = (t>=off)? s[t-off] : 0;
        __syncthreads();
        s[t] += a;
        __syncthreads();
    }
    if(t < NB_SCAN) bsum[t] = s[t] - v;   // exclusive scan of block sums
}

__global__ void k_scan(const int* __restrict__ deg, const int* __restrict__ bsum,
                       int* __restrict__ starts, float* __restrict__ dinv){
    __shared__ int s[256];
    int t = threadIdx.x; int i = blockIdx.x*256 + t;
    int d = (i<NN)? deg[i] : 0;
    s[t] = d; __syncthreads();
    for(int off=1; off<256; off<<=1){
        int a = (t>=off)? s[t-off] : 0;
        __syncthreads();
        s[t] += a;
        __syncthreads();
    }
    if(i < NN){
        starts[i] = bsum[blockIdx.x] + s[t] - d;   // exclusive
        dinv[i] = rsqrtf((float)(d + 1));          // +1 self-loop
    }
}

// ---------------- stage 2b: per-bucket LDS scatter, coalesced csr write ----------------
__global__ void __launch_bounds__(256) k_fill2(const int* __restrict__ bcnt,
                                               const uint32* __restrict__ staged,
                                               const int* __restrict__ starts,
                                               int* __restrict__ csr){
    __shared__ int cur[512];
    __shared__ int lcsr[BCAP];
    int b = blockIdx.x, t = threadIdx.x;
    int n0 = b*512;
    int base = starts[n0];
    for(int i = t; i < 512; i += 256){
        int n = n0 + i;
        cur[i] = (n < NN) ? starts[n] - base : 0;
    }
    __syncthreads();
    int cnt = min(bcnt[b], BCAP);
    const uint32* st = staged + (size_t)b*BCAP;
    for(int i = t; i < cnt; i += 256){
        uint32 u = st[i];
        int p = atomicAdd(&cur[u & 511u], 1);
        lcsr[p] = (int)(u >> BSH);
    }
    __syncthreads();
    for(int i = t; i < cnt; i += 256) csr[base + i] = lcsr[i];
}

// ---------------- BN constant folding ----------------
__global__ void k_const(const float* __restrict__ encB, const float* __restrict__ encG,
                        const float* __restrict__ encBe, const float* __restrict__ encM,
                        const float* __restrict__ encV,
                        const float* __restrict__ ep1b, const float* __restrict__ epG,
                        const float* __restrict__ epBe, const float* __restrict__ epM,
                        const float* __restrict__ epV,
                        float* __restrict__ foldEnc, float* __restrict__ foldPre){
    int j = threadIdx.x;
    if(j < 64){
        float s = encG[j]*rsqrtf(encV[j]+1e-5f);
        foldEnc[j]      = s;
        foldEnc[64+j]   = (encB[j]-encM[j])*s + encBe[j];
        float sp = epG[j]*rsqrtf(epV[j]+1e-5f);
        foldPre[j]      = sp;
        foldPre[64+j]   = sp;
        foldPre[128+j]  = sp*(ep1b[j]-epM[j]) + epBe[j];
        foldPre[192+j]  = 0.f;
    }
}

// ---------------- generic GEMV: thread-per-node, W staged in LDS ----------------
// PREMAP: W source is ep1W [128,64]; logical W[k][j] = j<64 ? ep1W[k][j] : ep1W[64+k][j-64]
template<int K, int JB, bool PREMAP, bool FOLD, bool RELU, bool OH>
__global__ void __launch_bounds__(256) k_gemv(const float* __restrict__ in,
                                              const float* __restrict__ W,
                                              const float* __restrict__ fold,
                                              void* __restrict__ outv){
    __shared__ float Ws[K*JB*64];
    __shared__ float Fs[2*JB*64];
    const int J = JB*64;
    for(int idx = threadIdx.x; idx < K*J; idx += 256){
        if(PREMAP){
            int k = idx / J, j = idx % J;   // J=128 here
            Ws[idx] = (j < 64) ? W[k*64 + j] : W[(64+k)*64 + (j-64)];
        } else {
            Ws[idx] = W[idx];
        }
    }
    if(FOLD){
        for(int idx = threadIdx.x; idx < 2*J; idx += 256) Fs[idx] = fold[idx];
    }
    __syncthreads();
    int n = blockIdx.x*256 + threadIdx.x;
    if(n >= NN) return;
    const float4* x4 = (const float4*)(in + (size_t)n*K);
    for(int jb = 0; jb < JB; jb++){
        float acc[64];
        #pragma unroll
        for(int j = 0; j < 64; j++) acc[j] = 0.f;
        for(int k4 = 0; k4 < K/4; k4++){
            float4 xv = x4[k4];
            #pragma unroll
            for(int kk = 0; kk < 4; kk++){
                float xs_ = (kk==0)?xv.x:(kk==1)?xv.y:(kk==2)?xv.z:xv.w;
                const float4* wrow = (const float4*)&Ws[(k4*4+kk)*J + jb*64];
                #pragma unroll
                for(int j4 = 0; j4 < 16; j4++){
                    float4 w = wrow[j4];
                    acc[4*j4+0] = fmaf(xs_, w.x, acc[4*j4+0]);
                    acc[4*j4+1] = fmaf(xs_, w.y, acc[4*j4+1]);
                    acc[4*j4+2] = fmaf(xs_, w.z, acc[4*j4+2]);
                    acc[4*j4+3] = fmaf(xs_, w.w, acc[4*j4+3]);
                }
            }
        }
        #pragma unroll
        for(int j4 = 0; j4 < 16; j4++){
            float vv[4];
            #pragma unroll
            for(int c = 0; c < 4; c++){
                int j = 4*j4 + c;
                float t = acc[j];
                if(FOLD) t = t*Fs[jb*64+j] + Fs[J + jb*64 + j];
                if(RELU) t = fmaxf(t, 0.f);
                vv[c] = t;
            }
            if(OH){
                ushort4 u;
                u.x = __half_as_ushort(__float2half_rn(vv[0]));
                u.y = __half_as_ushort(__float2half_rn(vv[1]));
                u.z = __half_as_ushort(__float2half_rn(vv[2]));
                u.w = __half_as_ushort(__float2half_rn(vv[3]));
                ((ushort4*)((unsigned short*)outv + (size_t)n*J + jb*64))[j4] = u;
            } else {
                float4 v;
                v.x = vv[0]; v.y = vv[1]; v.z = vv[2]; v.w = vv[3];
                ((float4*)((float*)outv + (size_t)n*J + jb*64))[j4] = v;
            }
        }
    }
}

// ---------------- GCN aggregation (fp16 hw): relu(sum_in + self + b) ----------------
__global__ void __launch_bounds__(256) k_agg(const __half* __restrict__ hw,
                                             const int* __restrict__ starts,
                                             const int* __restrict__ deg,
                                             const int* __restrict__ csr,
                                             const float* __restrict__ dinv,
                                             const float* __restrict__ bias,
                                             float* __restrict__ out){
    int t = threadIdx.x, w = t>>6, f = t&63;
    int n = blockIdx.x*4 + w;
    int s = starts[n], d = deg[n];
    float acc = 0.f;
    int i = 0;
    for(; i+3 < d; i += 4){                 // 4-way unroll for outstanding gathers
        int r0 = csr[s+i],   r1 = csr[s+i+1];
        int r2 = csr[s+i+2], r3 = csr[s+i+3];
        float v0 = __half2float(hw[(size_t)r0*64 + f]);
        float v1 = __half2float(hw[(size_t)r1*64 + f]);
        float v2 = __half2float(hw[(size_t)r2*64 + f]);
        float v3 = __half2float(hw[(size_t)r3*64 + f]);
        acc = fmaf(v0, dinv[r0], acc);
        acc = fmaf(v1, dinv[r1], acc);
        acc = fmaf(v2, dinv[r2], acc);
        acc = fmaf(v3, dinv[r3], acc);
    }
    for(; i < d; i++){
        int r0 = csr[s+i];
        acc = fmaf(__half2float(hw[(size_t)r0*64 + f]), dinv[r0], acc);
    }
    float dn = dinv[n];
    float self = __half2float(hw[(size_t)n*64 + f]);
    float v = acc*dn + self*dn*dn + bias[f];
    out[(size_t)n*64 + f] = fmaxf(v, 0.f);
}

// ---------------- edge predictor (factorized, fp16 pre): thread-per-edge ----------------
__global__ void __launch_bounds__(256) k_edge2(const __half* __restrict__ pre,
                                               const int* __restrict__ row,
                                               const int* __restrict__ col,
                                               const float* __restrict__ w2,
                                               const float* __restrict__ b2,
                                               float* __restrict__ out){
    __shared__ float w2s[64];
    __shared__ float b2s;
    if(threadIdx.x < 64) w2s[threadIdx.x] = w2[threadIdx.x];
    if(threadIdx.x == 64) b2s = b2[0];
    __syncthreads();
    int e = blockIdx.x*256 + threadIdx.x;
    if(e >= NE) return;
    int r = row[e], c = col[e];
    const uint4* pa = (const uint4*)(pre + (size_t)r*128);        // A half: 128B
    const uint4* pb = (const uint4*)(pre + (size_t)c*128 + 64);   // B half: 128B
    float z = 0.f;
    #pragma unroll
    for(int q = 0; q < 8; q++){
        uint4 ua = pa[q], ub = pb[q];
        const __half2* ah = (const __half2*)&ua;
        const __half2* bh = (const __half2*)&ub;
        #pragma unroll
        for(int u = 0; u < 4; u++){
            float2 a2 = __half22float2(ah[u]);
            float2 b2v = __half22float2(bh[u]);
            int j = q*8 + u*2;
            z = fmaf(fmaxf(a2.x + b2v.x, 0.f), w2s[j],   z);
            z = fmaf(fmaxf(a2.y + b2v.y, 0.f), w2s[j+1], z);
        }
    }
    z += b2s;
    out[e] = 1.f / (1.f + __expf(-z));
}

// ---------------- launch ----------------

extern "C" void kernel_launch(void* const* d_in, const int* in_sizes, int n_in,
                              void* d_out, int out_size, void* d_ws, size_t ws_size,
                              hipStream_t stream){
    const float* x   = (const float*)d_in[0];
    const int* ei    = (const int*)d_in[1];
    const int* row   = ei;
    const int* col   = ei + NE;
    const float* encW = (const float*)d_in[2],  *encB = (const float*)d_in[3];
    const float* encG = (const float*)d_in[4],  *encBe= (const float*)d_in[5];
    const float* encM = (const float*)d_in[6],  *encV = (const float*)d_in[7];
    const float* c1W  = (const float*)d_in[8],  *c1b  = (const float*)d_in[9];
    const float* c2W  = (const float*)d_in[10], *c2b  = (const float*)d_in[11];
    const float* ep1W = (const float*)d_in[12], *ep1b = (const float*)d_in[13];
    const float* epG  = (const float*)d_in[14], *epBe = (const float*)d_in[15];
    const float* epM  = (const float*)d_in[16], *epV  = (const float*)d_in[17];
    const float* ep2W = (const float*)d_in[18], *ep2b = (const float*)d_in[19];

    char* wsc = (char*)d_ws;
    size_t o = 0;
    auto alloc = [&](size_t bytes)->void*{
        void* p = wsc + o; o += (bytes + 255) & ~(size_t)255; return p;
    };
    int*    deg     = (int*)   alloc((size_t)NN*4);
    int*    starts  = (int*)   alloc((size_t)NN*4);
    int*    bsum    = (int*)   alloc(1024*4);
    int*    bcnt    = (int*)   alloc((size_t)NBUCK*4);
    int*    csr     = (int*)   alloc((size_t)NE*4);
    uint32* staged  = (uint32*)alloc((size_t)NBUCK*BCAP*4);   // 8.0 MB
    float*  dinv    = (float*) alloc((size_t)NN*4);
    float*  foldEnc = (float*) alloc(128*4);
    float*  foldPre = (float*) alloc(256*4);
    float*  bufA    = (float*) alloc((size_t)NN*64*4);        // fp32 h buffer (25.6 MB)
    __half* bufB    = (__half*)alloc((size_t)NN*64*2);        // fp16 hw buffer (12.8 MB)
    // pre[N,128] fp16 (25.6 MB) aliases bufA (dead after conv2 gemv)
    __half* preh    = (__half*)bufA;
    // total ~54 MB of d_ws

    float* outp = (float*)d_out;               // [NN*64] node emb | [NE] edge preds
    float* node_out = outp;
    float* edge_out = outp + (size_t)NN*64;

    hipMemsetAsync(bcnt, 0, (size_t)NBUCK*4, stream);
    k_part <<<NCHUNK,  256, 0, stream>>>(row, col, bcnt, staged);
    k_hist <<<NBUCK,   256, 0, stream>>>(bcnt, staged, deg);
    k_bsum <<<NB_SCAN, 256, 0, stream>>>(deg, bsum);
    k_top  <<<1,       512, 0, stream>>>(bsum);
    k_scan <<<NB_SCAN, 256, 0, stream>>>(deg, bsum, starts, dinv);
    k_fill2<<<NBUCK,   256, 0, stream>>>(bcnt, staged, starts, csr);
    k_const<<<1, 64, 0, stream>>>(encB, encG, encBe, encM, encV,
                                  ep1b, epG, epBe, epM, epV, foldEnc, foldPre);

    // encoder: relu(bn(x @ encW + b)) -> fp32 bufA
    k_gemv<128,1,false,true,true,false><<<NB_SCAN, 256, 0, stream>>>(x, encW, foldEnc, bufA);

    // conv1: hw fp16 -> aggregate fp32
    k_gemv<64,1,false,false,false,true><<<NB_SCAN, 256, 0, stream>>>(bufA, c1W, nullptr, bufB);
    k_agg  <<<NN/4, 256, 0, stream>>>(bufB, starts, deg, csr, dinv, c1b, bufA);

    // conv2
    k_gemv<64,1,false,false,false,true><<<NB_SCAN, 256, 0, stream>>>(bufA, c2W, nullptr, bufB);
    k_agg  <<<NN/4, 256, 0, stream>>>(bufB, starts, deg, csr, dinv, c2b, node_out);

    // edge predictor precompute -> fp16 pre
    k_gemv<64,2,true,true,false,true><<<NB_SCAN, 256, 0, stream>>>(node_out, ep1W, foldPre, preh);

    // per-edge: sigmoid(sum relu(preA[r]+preB[c])*w2 + b2)
    k_edge2<<<NE/256, 256, 0, stream>>>(preh, row, col, ep2W, ep2b, edge_out);
}